// Round 1
// baseline (419.739 us; speedup 1.0000x reference)
//
#include <hip/hip_runtime.h>
#include <cstdint>
#include <cstddef>

typedef short short8 __attribute__((ext_vector_type(8)));
typedef float f32x4 __attribute__((ext_vector_type(4)));

#define LOG2E 1.44269504088896340736f

__device__ inline unsigned short f2bf(float f) {
  unsigned int u = __float_as_uint(f);
  u += 0x7FFFu + ((u >> 16) & 1u);
  return (unsigned short)(u >> 16);
}
__device__ inline float bf2f(unsigned short s) {
  return __uint_as_float(((unsigned int)s) << 16);
}

// MFMA via inline asm (dodges builtin-signature risk). D==C tied ("+v") is the
// ISA-sanctioned accumulate-in-place form.
__device__ inline void mfma16(f32x4 &acc, short8 a, short8 b) {
  asm volatile("v_mfma_f32_16x16x32_bf16 %0, %1, %2, %0"
               : "+v"(acc)
               : "v"(a), "v"(b));
}
// Hazard fences: fake data-dep on acc pins ordering around the asm MFMAs.
__device__ inline void fence_after_mfma(f32x4 &x) {
  asm volatile("s_nop 7" : "+v"(x));
  asm volatile("s_nop 7" : "+v"(x));
}
__device__ inline void fence_before_mfma(f32x4 &x) {
  asm volatile("s_nop 1" : "+v"(x));
}

// ---------------------------------------------------------------------------
// Kernel 1: QKV projection. x[16384][256] f32 @ W[256][64]x3 -> per-row 192
// outputs. Tiled GEMM: BM=64 rows, BN=192 (all cols), BK=32, 256 threads,
// thread tile 4x12. Epilogue: LDS round-trip, emit bf16 hi/lo for Q (pre-
// scaled by log2e) and K, bf16 for V stored TRANSPOSED Vt[b][64][4096].
// ---------------------------------------------------------------------------
__global__ __launch_bounds__(256) void proj_qkv_kernel(
    const float* __restrict__ x,
    const float* __restrict__ Wq, const float* __restrict__ bq,
    const float* __restrict__ Wk, const float* __restrict__ bk,
    const float* __restrict__ Wv, const float* __restrict__ bv,
    unsigned short* __restrict__ Qh, unsigned short* __restrict__ Ql,
    unsigned short* __restrict__ Kh, unsigned short* __restrict__ Kl,
    unsigned short* __restrict__ Vt)
{
  __shared__ __align__(16) char sm[49152];
  float* xt   = (float*)sm;            // [32][64]  (k-major, transposed)
  float* Wl   = (float*)(sm + 8192);   // [32][192]
  float* accL = (float*)sm;            // [64][192] (epilogue reuse)

  const int t  = threadIdx.x;
  const int m0 = blockIdx.x * 64;
  const int rg = t >> 4;   // row group: rows rg*4 .. rg*4+3
  const int cg = t & 15;   // col group: cols cg*12 .. cg*12+11

  float acc[4][12];
#pragma unroll
  for (int a = 0; a < 4; ++a)
#pragma unroll
    for (int c = 0; c < 12; ++c) acc[a][c] = 0.0f;

  uint4 xr[2], wr[6];

  auto load_tile = [&](int k0) {
#pragma unroll
    for (int i = 0; i < 2; ++i) {
      int sl = t + i * 256;            // 512 slots of 16B: x tile 64x32 f32
      int r = sl >> 3, ks = sl & 7;
      xr[i] = *(const uint4*)(x + (size_t)(m0 + r) * 256 + k0 + 4 * ks);
    }
#pragma unroll
    for (int i = 0; i < 6; ++i) {
      int sl = t + i * 256;            // 1536 slots: W tile 32x192 f32
      int kk = sl / 48, cs = sl % 48;
      int col0 = cs * 4;
      const float* Wp = (col0 < 64) ? Wq : ((col0 < 128) ? Wk : Wv);
      wr[i] = *(const uint4*)(Wp + (k0 + kk) * 64 + (col0 & 63));
    }
  };
  auto store_tile = [&]() {
#pragma unroll
    for (int i = 0; i < 2; ++i) {
      int sl = t + i * 256;
      int r = sl >> 3, ks = sl & 7;
      xt[(4 * ks + 0) * 64 + r] = __uint_as_float(xr[i].x);
      xt[(4 * ks + 1) * 64 + r] = __uint_as_float(xr[i].y);
      xt[(4 * ks + 2) * 64 + r] = __uint_as_float(xr[i].z);
      xt[(4 * ks + 3) * 64 + r] = __uint_as_float(xr[i].w);
    }
#pragma unroll
    for (int i = 0; i < 6; ++i) {
      int sl = t + i * 256;
      int kk = sl / 48, cs = sl % 48;
      *(uint4*)(Wl + kk * 192 + 4 * cs) = wr[i];
    }
  };

  load_tile(0);
#pragma unroll 1
  for (int it = 0; it < 8; ++it) {
    __syncthreads();
    store_tile();
    __syncthreads();
    if (it < 7) load_tile((it + 1) * 32);
#pragma unroll 1
    for (int kk = 0; kk < 32; ++kk) {
      f32x4 xv = *(const f32x4*)(xt + kk * 64 + 4 * rg);
      f32x4 w0 = *(const f32x4*)(Wl + kk * 192 + 12 * cg);
      f32x4 w1 = *(const f32x4*)(Wl + kk * 192 + 12 * cg + 4);
      f32x4 w2 = *(const f32x4*)(Wl + kk * 192 + 12 * cg + 8);
#pragma unroll
      for (int a = 0; a < 4; ++a) {
#pragma unroll
        for (int u = 0; u < 4; ++u) {
          acc[a][u]     += xv[a] * w0[u];
          acc[a][4 + u] += xv[a] * w1[u];
          acc[a][8 + u] += xv[a] * w2[u];
        }
      }
    }
  }

  // ---- epilogue: acc -> LDS -> coalesced bf16 stores ----
  __syncthreads();
#pragma unroll
  for (int a = 0; a < 4; ++a)
#pragma unroll
    for (int c = 0; c < 12; ++c)
      accL[(rg * 4 + a) * 192 + cg * 12 + c] = acc[a][c];
  __syncthreads();

  const int b_idx = m0 >> 12;
  const int s0    = m0 & 4095;

  // Q and K: thread -> row r = t>>2, 16-col chunk c0 = (t&3)*16
  {
    const int r  = t >> 2;
    const int c0 = (t & 3) * 16;
    unsigned int hq[8], lq[8], hk[8], lk[8];
#pragma unroll
    for (int p = 0; p < 8; ++p) {
      // Q cols c0+2p, c0+2p+1
      float q0 = (accL[r * 192 + c0 + 2 * p]     + bq[c0 + 2 * p])     * LOG2E;
      float q1 = (accL[r * 192 + c0 + 2 * p + 1] + bq[c0 + 2 * p + 1]) * LOG2E;
      unsigned short h0 = f2bf(q0), h1 = f2bf(q1);
      unsigned short l0 = f2bf(q0 - bf2f(h0)), l1 = f2bf(q1 - bf2f(h1));
      hq[p] = (unsigned int)h0 | ((unsigned int)h1 << 16);
      lq[p] = (unsigned int)l0 | ((unsigned int)l1 << 16);
      // K cols 64 + c0+2p
      float k0v = accL[r * 192 + 64 + c0 + 2 * p]     + bk[c0 + 2 * p];
      float k1v = accL[r * 192 + 64 + c0 + 2 * p + 1] + bk[c0 + 2 * p + 1];
      unsigned short kh0 = f2bf(k0v), kh1 = f2bf(k1v);
      unsigned short kl0 = f2bf(k0v - bf2f(kh0)), kl1 = f2bf(k1v - bf2f(kh1));
      hk[p] = (unsigned int)kh0 | ((unsigned int)kh1 << 16);
      lk[p] = (unsigned int)kl0 | ((unsigned int)kl1 << 16);
    }
    size_t o = (size_t)(m0 + r) * 64 + c0;
    *(uint4*)(Qh + o)     = make_uint4(hq[0], hq[1], hq[2], hq[3]);
    *(uint4*)(Qh + o + 8) = make_uint4(hq[4], hq[5], hq[6], hq[7]);
    *(uint4*)(Ql + o)     = make_uint4(lq[0], lq[1], lq[2], lq[3]);
    *(uint4*)(Ql + o + 8) = make_uint4(lq[4], lq[5], lq[6], lq[7]);
    *(uint4*)(Kh + o)     = make_uint4(hk[0], hk[1], hk[2], hk[3]);
    *(uint4*)(Kh + o + 8) = make_uint4(hk[4], hk[5], hk[6], hk[7]);
    *(uint4*)(Kl + o)     = make_uint4(lk[0], lk[1], lk[2], lk[3]);
    *(uint4*)(Kl + o + 8) = make_uint4(lk[4], lk[5], lk[6], lk[7]);
  }

  // V transposed: thread -> col = t>>2, rows r0..r0+15
  {
    const int colv = t >> 2;
    const int r0   = (t & 3) * 16;
    unsigned int hv[8];
#pragma unroll
    for (int p = 0; p < 8; ++p) {
      float v0 = accL[(r0 + 2 * p) * 192 + 128 + colv]     + bv[colv];
      float v1 = accL[(r0 + 2 * p + 1) * 192 + 128 + colv] + bv[colv];
      hv[p] = (unsigned int)f2bf(v0) | ((unsigned int)f2bf(v1) << 16);
    }
    size_t o = ((size_t)b_idx * 64 + colv) * 4096 + s0 + r0;
    *(uint4*)(Vt + o)     = make_uint4(hv[0], hv[1], hv[2], hv[3]);
    *(uint4*)(Vt + o + 8) = make_uint4(hv[4], hv[5], hv[6], hv[7]);
  }
}

// ---------------------------------------------------------------------------
// Kernel 2: two-pass flash attention with mean-threshold mask.
// Grid (64 q-tiles, 4 batches), 256 threads = 4 waves x 16 q-rows.
// Pass 1: online (m, Z) per row.  Pass 2: p = exp2(s-m), mask p > Z/4096,
// P through swizzled wave-private LDS -> PV MFMA, out = acc/Z.
// LDS: Kh@0 (8K), Kl@8192, Vt@16384 (8K), P@24576 (4x2K), rZ@32768 (256B).
// All K/V/P tiles 16B-swizzled: slot ^= (row&7).
// ---------------------------------------------------------------------------
#define KH_OFF 0
#define KL_OFF 8192
#define VT_OFF 16384
#define P_OFF  24576
#define Z_OFF  32768

__global__ __launch_bounds__(256) void fused_attn_kernel(
    const unsigned short* __restrict__ Qh, const unsigned short* __restrict__ Ql,
    const unsigned short* __restrict__ Kh, const unsigned short* __restrict__ Kl,
    const unsigned short* __restrict__ Vt,
    float* __restrict__ out)
{
  __shared__ __align__(16) char sm[33024];

  const int t    = threadIdx.x;
  const int wv   = t >> 6;
  const int lane = t & 63;
  const int li   = lane & 15;
  const int lg   = lane >> 4;
  const int b    = blockIdx.y;
  const int q0   = blockIdx.x * 64 + wv * 16;
  const int sw   = li & 7;

  // fragment slot offsets (bytes within a 128B row), swizzled
  const int slotA0 = ((lg)     ^ sw) << 4;   // k-chunk 0
  const int slotA1 = ((4 + lg) ^ sw) << 4;   // k-chunk 1

  // Q fragments (hi/lo), loaded once. lane: row=li, k = 32c + 8*lg + u.
  short8 qh0, qh1, ql0, ql1;
  {
    size_t base = ((size_t)(b * 4096 + q0 + li)) * 64 + lg * 8;
    qh0 = *(const short8*)(Qh + base);
    qh1 = *(const short8*)(Qh + base + 32);
    ql0 = *(const short8*)(Ql + base);
    ql1 = *(const short8*)(Ql + base + 32);
  }

  // staging slots: 512 x 16B per 8KB tile; thread handles slots t, t+256
  int sls[2] = { t, t + 256 };
  int st_off[2];
#pragma unroll
  for (int i = 0; i < 2; ++i) {
    int row = sls[i] >> 3, k16 = sls[i] & 7;
    st_off[i] = row * 128 + ((k16 ^ (row & 7)) << 4);
  }
  const size_t kbase = (size_t)b * 262144;  // batch base in K arrays (elems)

  // ===================== PASS 1: row stats (m, Z) =====================
  float m = -3.0e38f, Z = 0.0f;
  uint4 rkh[2], rkl[2];
#pragma unroll
  for (int i = 0; i < 2; ++i) {
    rkh[i] = *(const uint4*)(Kh + kbase + sls[i] * 8);
    rkl[i] = *(const uint4*)(Kl + kbase + sls[i] * 8);
  }
#pragma unroll 1
  for (int jt = 0; jt < 64; ++jt) {
    __syncthreads();
#pragma unroll
    for (int i = 0; i < 2; ++i) {
      *(uint4*)(sm + KH_OFF + st_off[i]) = rkh[i];
      *(uint4*)(sm + KL_OFF + st_off[i]) = rkl[i];
    }
    __syncthreads();
    if (jt + 1 < 64) {
#pragma unroll
      for (int i = 0; i < 2; ++i) {
        rkh[i] = *(const uint4*)(Kh + kbase + (size_t)(jt + 1) * 4096 + sls[i] * 8);
        rkl[i] = *(const uint4*)(Kl + kbase + (size_t)(jt + 1) * 4096 + sls[i] * 8);
      }
    }
#pragma unroll
    for (int s = 0; s < 4; ++s) {
      f32x4 acc = {0.f, 0.f, 0.f, 0.f};
      fence_before_mfma(acc);
      const int rowb = (16 * s + li) * 128;
      short8 ah0 = *(const short8*)(sm + KH_OFF + rowb + slotA0);
      short8 al0 = *(const short8*)(sm + KL_OFF + rowb + slotA0);
      short8 ah1 = *(const short8*)(sm + KH_OFF + rowb + slotA1);
      short8 al1 = *(const short8*)(sm + KL_OFF + rowb + slotA1);
      mfma16(acc, ah0, qh0); mfma16(acc, ah0, ql0); mfma16(acc, al0, qh0);
      mfma16(acc, ah1, qh1); mfma16(acc, ah1, ql1); mfma16(acc, al1, qh1);
      fence_after_mfma(acc);
      float mx = fmaxf(fmaxf(acc[0], acc[1]), fmaxf(acc[2], acc[3]));
      float nm = fmaxf(m, mx);
      float sc = __builtin_exp2f(m - nm);
      Z = Z * sc + __builtin_exp2f(acc[0] - nm) + __builtin_exp2f(acc[1] - nm)
                 + __builtin_exp2f(acc[2] - nm) + __builtin_exp2f(acc[3] - nm);
      m = nm;
    }
  }
  // combine the 4 lanes (lg groups) holding the same row i=li
#pragma unroll
  for (int off = 16; off < 64; off <<= 1) {
    float om = __shfl_xor(m, off, 64);
    float oZ = __shfl_xor(Z, off, 64);
    float nm = fmaxf(m, om);
    Z = Z * __builtin_exp2f(m - nm) + oZ * __builtin_exp2f(om - nm);
    m = nm;
  }
  const float thr = Z * (1.0f / 4096.0f);
  if (lane < 16) *(float*)(sm + Z_OFF + (wv * 16 + lane) * 4) = 1.0f / Z;

  // ===================== PASS 2: masked PV =====================
  f32x4 o0 = {0.f,0.f,0.f,0.f}, o1 = {0.f,0.f,0.f,0.f};
  f32x4 o2 = {0.f,0.f,0.f,0.f}, o3 = {0.f,0.f,0.f,0.f};
  fence_before_mfma(o0); fence_before_mfma(o1);
  fence_before_mfma(o2); fence_before_mfma(o3);

  uint4 rvt[2];
#pragma unroll
  for (int i = 0; i < 2; ++i) {
    rkh[i] = *(const uint4*)(Kh + kbase + sls[i] * 8);
    rkl[i] = *(const uint4*)(Kl + kbase + sls[i] * 8);
    rvt[i] = *(const uint4*)(Vt + ((size_t)b * 64 + (sls[i] >> 3)) * 4096 + (sls[i] & 7) * 8);
  }
  const int pbase = P_OFF + wv * 2048 + li * 128;
  const int pwslot = ((lg & 1) * 8);
#pragma unroll 1
  for (int jt = 0; jt < 64; ++jt) {
    __syncthreads();
#pragma unroll
    for (int i = 0; i < 2; ++i) {
      *(uint4*)(sm + KH_OFF + st_off[i]) = rkh[i];
      *(uint4*)(sm + KL_OFF + st_off[i]) = rkl[i];
      *(uint4*)(sm + VT_OFF + st_off[i]) = rvt[i];
    }
    __syncthreads();
    if (jt + 1 < 64) {
#pragma unroll
      for (int i = 0; i < 2; ++i) {
        rkh[i] = *(const uint4*)(Kh + kbase + (size_t)(jt + 1) * 4096 + sls[i] * 8);
        rkl[i] = *(const uint4*)(Kl + kbase + (size_t)(jt + 1) * 4096 + sls[i] * 8);
        rvt[i] = *(const uint4*)(Vt + ((size_t)b * 64 + (sls[i] >> 3)) * 4096
                                 + (size_t)(jt + 1) * 64 + (sls[i] & 7) * 8);
      }
    }
    // scores -> masked P (bf16) into wave-private swizzled LDS
#pragma unroll
    for (int s = 0; s < 4; ++s) {
      f32x4 acc = {0.f, 0.f, 0.f, 0.f};
      fence_before_mfma(acc);
      const int rowb = (16 * s + li) * 128;
      short8 ah0 = *(const short8*)(sm + KH_OFF + rowb + slotA0);
      short8 al0 = *(const short8*)(sm + KL_OFF + rowb + slotA0);
      short8 ah1 = *(const short8*)(sm + KH_OFF + rowb + slotA1);
      short8 al1 = *(const short8*)(sm + KL_OFF + rowb + slotA1);
      mfma16(acc, ah0, qh0); mfma16(acc, ah0, ql0); mfma16(acc, al0, qh0);
      mfma16(acc, ah1, qh1); mfma16(acc, ah1, ql1); mfma16(acc, al1, qh1);
      fence_after_mfma(acc);
      float p0 = __builtin_exp2f(acc[0] - m); p0 = (p0 > thr) ? p0 : 0.0f;
      float p1 = __builtin_exp2f(acc[1] - m); p1 = (p1 > thr) ? p1 : 0.0f;
      float p2 = __builtin_exp2f(acc[2] - m); p2 = (p2 > thr) ? p2 : 0.0f;
      float p3 = __builtin_exp2f(acc[3] - m); p3 = (p3 > thr) ? p3 : 0.0f;
      uint2 pw;
      pw.x = (unsigned int)f2bf(p0) | ((unsigned int)f2bf(p1) << 16);
      pw.y = (unsigned int)f2bf(p2) | ((unsigned int)f2bf(p3) << 16);
      *(uint2*)(sm + pbase + (((2 * s + (lg >> 1)) ^ sw) << 4) + pwslot) = pw;
    }
    // PV: A = P (rows=i), B = Vt (cols), contraction over this tile's 64 j
    short8 pa0 = *(const short8*)(sm + pbase + slotA0);
    short8 pa1 = *(const short8*)(sm + pbase + slotA1);
    {
      short8 vb0 = *(const short8*)(sm + VT_OFF + (li) * 128 + slotA0);
      short8 vb1 = *(const short8*)(sm + VT_OFF + (li) * 128 + slotA1);
      mfma16(o0, pa0, vb0); mfma16(o0, pa1, vb1);
      vb0 = *(const short8*)(sm + VT_OFF + (16 + li) * 128 + slotA0);
      vb1 = *(const short8*)(sm + VT_OFF + (16 + li) * 128 + slotA1);
      mfma16(o1, pa0, vb0); mfma16(o1, pa1, vb1);
      vb0 = *(const short8*)(sm + VT_OFF + (32 + li) * 128 + slotA0);
      vb1 = *(const short8*)(sm + VT_OFF + (32 + li) * 128 + slotA1);
      mfma16(o2, pa0, vb0); mfma16(o2, pa1, vb1);
      vb0 = *(const short8*)(sm + VT_OFF + (48 + li) * 128 + slotA0);
      vb1 = *(const short8*)(sm + VT_OFF + (48 + li) * 128 + slotA1);
      mfma16(o3, pa0, vb0); mfma16(o3, pa1, vb1);
    }
  }
  fence_after_mfma(o0); fence_after_mfma(o1);
  fence_after_mfma(o2); fence_after_mfma(o3);

  // epilogue: out[row = q0 + lg*4+r][col = 16*tt + li] = o[tt][r] / Z[row]
  f32x4 rz4 = *(const f32x4*)(sm + Z_OFF + wv * 64 + lg * 16);
  const size_t ob = ((size_t)b * 4096 + q0) * 64;
#pragma unroll
  for (int r = 0; r < 4; ++r) {
    size_t rowoff = ob + (size_t)(lg * 4 + r) * 64 + li;
    out[rowoff]      = o0[r] * rz4[r];
    out[rowoff + 16] = o1[r] * rz4[r];
    out[rowoff + 32] = o2[r] * rz4[r];
    out[rowoff + 48] = o3[r] * rz4[r];
  }
}

extern "C" void kernel_launch(void* const* d_in, const int* in_sizes, int n_in,
                              void* d_out, int out_size, void* d_ws, size_t ws_size,
                              hipStream_t stream) {
  (void)in_sizes; (void)n_in; (void)out_size; (void)ws_size;
  const float* x  = (const float*)d_in[0];
  const float* Wq = (const float*)d_in[1];
  const float* bq = (const float*)d_in[2];
  const float* Wk = (const float*)d_in[3];
  const float* bk = (const float*)d_in[4];
  const float* Wv = (const float*)d_in[5];
  const float* bv = (const float*)d_in[6];
  float* out = (float*)d_out;

  unsigned short* ws = (unsigned short*)d_ws;
  const size_t N = (size_t)16384 * 64;   // 1,048,576 elements per array
  unsigned short* Qh = ws;
  unsigned short* Ql = ws + N;
  unsigned short* Kh = ws + 2 * N;
  unsigned short* Kl = ws + 3 * N;
  unsigned short* Vt = ws + 4 * N;       // [B][64][4096]

  proj_qkv_kernel<<<dim3(256), dim3(256), 0, stream>>>(
      x, Wq, bq, Wk, bk, Wv, bv, Qh, Ql, Kh, Kl, Vt);
  fused_attn_kernel<<<dim3(64, 4), dim3(256), 0, stream>>>(
      Qh, Ql, Kh, Kl, Vt, out);
}

// Round 2
// 348.081 us; speedup vs baseline: 1.2059x; 1.2059x over previous
//
#include <hip/hip_runtime.h>
#include <cstdint>
#include <cstddef>

typedef short short8 __attribute__((ext_vector_type(8)));
typedef float f32x4 __attribute__((ext_vector_type(4)));
typedef float f32x2 __attribute__((ext_vector_type(2)));

#define LOG2E 1.44269504088896340736f
#define MASK_THR 2.44140625e-4f   // 2^-12 == 1/4096

__device__ inline unsigned short f2bf(float f) {
  unsigned int u = __float_as_uint(f);
  u += 0x7FFFu + ((u >> 16) & 1u);
  return (unsigned short)(u >> 16);
}
__device__ inline float bf2f(unsigned short s) {
  return __uint_as_float(((unsigned int)s) << 16);
}

__device__ inline void mfma16(f32x4 &acc, short8 a, short8 b) {
  asm volatile("v_mfma_f32_16x16x32_bf16 %0, %1, %2, %0"
               : "+v"(acc)
               : "v"(a), "v"(b));
}
__device__ inline void fence_after_mfma(f32x4 &x) {
  asm volatile("s_nop 7" : "+v"(x));
  asm volatile("s_nop 7" : "+v"(x));
}
__device__ inline void fence_before_mfma(f32x4 &x) {
  asm volatile("s_nop 1" : "+v"(x));
}

// ---------------------------------------------------------------------------
// Kernel 1: QKV projection. BM=32 rows/block -> 512 blocks (2+ blocks/CU).
// BN=192 (all of Q|K|V), BK=32, 256 threads, thread tile 2x12.
// Epilogue: LDS round-trip; Q (pre-scaled log2e) and K as bf16 hi/lo;
// V bf16 stored transposed Vt[b][64][4096].
// ---------------------------------------------------------------------------
__global__ __launch_bounds__(256) void proj_qkv_kernel(
    const float* __restrict__ x,
    const float* __restrict__ Wq, const float* __restrict__ bq,
    const float* __restrict__ Wk, const float* __restrict__ bk,
    const float* __restrict__ Wv, const float* __restrict__ bv,
    unsigned short* __restrict__ Qh, unsigned short* __restrict__ Ql,
    unsigned short* __restrict__ Kh, unsigned short* __restrict__ Kl,
    unsigned short* __restrict__ Vt)
{
  __shared__ __align__(16) char sm[28672];
  float* xt   = (float*)sm;            // [32 k][32 r] transposed
  float* Wl   = (float*)(sm + 4096);   // [32 k][192 c]
  float* accL = (float*)sm;            // [32 r][192 c] epilogue reuse (24KB)

  const int t  = threadIdx.x;
  const int m0 = blockIdx.x * 32;
  const int rg = t >> 4;   // 16 row-groups of 2 rows
  const int cg = t & 15;   // 16 col-groups of 12 cols

  float acc[2][12];
#pragma unroll
  for (int a = 0; a < 2; ++a)
#pragma unroll
    for (int c = 0; c < 12; ++c) acc[a][c] = 0.0f;

  uint4 xr, wr[6];

  auto load_tile = [&](int k0) {
    {
      int r = t >> 3, ks = t & 7;      // 256 slots: 32 rows x 8 k-chunks
      xr = *(const uint4*)(x + (size_t)(m0 + r) * 256 + k0 + 4 * ks);
    }
#pragma unroll
    for (int i = 0; i < 6; ++i) {
      int sl = t + i * 256;            // 1536 slots: W tile 32x192 f32
      int kk = sl / 48, cs = sl % 48;
      int col0 = cs * 4;
      const float* Wp = (col0 < 64) ? Wq : ((col0 < 128) ? Wk : Wv);
      wr[i] = *(const uint4*)(Wp + (k0 + kk) * 64 + (col0 & 63));
    }
  };
  auto store_tile = [&]() {
    {
      int r = t >> 3, ks = t & 7;
      xt[(4 * ks + 0) * 32 + r] = __uint_as_float(xr.x);
      xt[(4 * ks + 1) * 32 + r] = __uint_as_float(xr.y);
      xt[(4 * ks + 2) * 32 + r] = __uint_as_float(xr.z);
      xt[(4 * ks + 3) * 32 + r] = __uint_as_float(xr.w);
    }
#pragma unroll
    for (int i = 0; i < 6; ++i) {
      int sl = t + i * 256;
      int kk = sl / 48, cs = sl % 48;
      *(uint4*)(Wl + kk * 192 + 4 * cs) = wr[i];
    }
  };

  load_tile(0);
#pragma unroll 1
  for (int it = 0; it < 8; ++it) {
    __syncthreads();
    store_tile();
    __syncthreads();
    if (it < 7) load_tile((it + 1) * 32);
#pragma unroll 1
    for (int kk = 0; kk < 32; ++kk) {
      f32x2 xv = *(const f32x2*)(xt + kk * 32 + 2 * rg);
      f32x4 w0 = *(const f32x4*)(Wl + kk * 192 + 12 * cg);
      f32x4 w1 = *(const f32x4*)(Wl + kk * 192 + 12 * cg + 4);
      f32x4 w2 = *(const f32x4*)(Wl + kk * 192 + 12 * cg + 8);
#pragma unroll
      for (int a = 0; a < 2; ++a) {
#pragma unroll
        for (int u = 0; u < 4; ++u) {
          acc[a][u]     += xv[a] * w0[u];
          acc[a][4 + u] += xv[a] * w1[u];
          acc[a][8 + u] += xv[a] * w2[u];
        }
      }
    }
  }

  // ---- epilogue ----
  __syncthreads();
#pragma unroll
  for (int a = 0; a < 2; ++a)
#pragma unroll
    for (int c = 0; c < 12; ++c)
      accL[(rg * 2 + a) * 192 + cg * 12 + c] = acc[a][c];
  __syncthreads();

  const int b_idx = m0 >> 12;
  const int s0    = m0 & 4095;

  if (t < 128) {
    // Q and K: row r = t>>2 in [0,32), 16-col chunk c0 = (t&3)*16
    const int r  = t >> 2;
    const int c0 = (t & 3) * 16;
    unsigned int hq[8], lq[8], hk[8], lk[8];
#pragma unroll
    for (int p = 0; p < 8; ++p) {
      float q0 = (accL[r * 192 + c0 + 2 * p]     + bq[c0 + 2 * p])     * LOG2E;
      float q1 = (accL[r * 192 + c0 + 2 * p + 1] + bq[c0 + 2 * p + 1]) * LOG2E;
      unsigned short h0 = f2bf(q0), h1 = f2bf(q1);
      unsigned short l0 = f2bf(q0 - bf2f(h0)), l1 = f2bf(q1 - bf2f(h1));
      hq[p] = (unsigned int)h0 | ((unsigned int)h1 << 16);
      lq[p] = (unsigned int)l0 | ((unsigned int)l1 << 16);
      float k0v = accL[r * 192 + 64 + c0 + 2 * p]     + bk[c0 + 2 * p];
      float k1v = accL[r * 192 + 64 + c0 + 2 * p + 1] + bk[c0 + 2 * p + 1];
      unsigned short kh0 = f2bf(k0v), kh1 = f2bf(k1v);
      unsigned short kl0 = f2bf(k0v - bf2f(kh0)), kl1 = f2bf(k1v - bf2f(kh1));
      hk[p] = (unsigned int)kh0 | ((unsigned int)kh1 << 16);
      lk[p] = (unsigned int)kl0 | ((unsigned int)kl1 << 16);
    }
    size_t o = (size_t)(m0 + r) * 64 + c0;
    *(uint4*)(Qh + o)     = make_uint4(hq[0], hq[1], hq[2], hq[3]);
    *(uint4*)(Qh + o + 8) = make_uint4(hq[4], hq[5], hq[6], hq[7]);
    *(uint4*)(Ql + o)     = make_uint4(lq[0], lq[1], lq[2], lq[3]);
    *(uint4*)(Ql + o + 8) = make_uint4(lq[4], lq[5], lq[6], lq[7]);
    *(uint4*)(Kh + o)     = make_uint4(hk[0], hk[1], hk[2], hk[3]);
    *(uint4*)(Kh + o + 8) = make_uint4(hk[4], hk[5], hk[6], hk[7]);
    *(uint4*)(Kl + o)     = make_uint4(lk[0], lk[1], lk[2], lk[3]);
    *(uint4*)(Kl + o + 8) = make_uint4(lk[4], lk[5], lk[6], lk[7]);
  } else {
    // V transposed: u = t-128: col = u>>1 in [0,64), rows r0 = (u&1)*16 .. +15
    const int u2   = t - 128;
    const int colv = u2 >> 1;
    const int r0   = (u2 & 1) * 16;
    unsigned int hv[8];
#pragma unroll
    for (int p = 0; p < 8; ++p) {
      float v0 = accL[(r0 + 2 * p) * 192 + 128 + colv]     + bv[colv];
      float v1 = accL[(r0 + 2 * p + 1) * 192 + 128 + colv] + bv[colv];
      hv[p] = (unsigned int)f2bf(v0) | ((unsigned int)f2bf(v1) << 16);
    }
    size_t o = ((size_t)b_idx * 64 + colv) * 4096 + s0 + r0;
    *(uint4*)(Vt + o)     = make_uint4(hv[0], hv[1], hv[2], hv[3]);
    *(uint4*)(Vt + o + 8) = make_uint4(hv[4], hv[5], hv[6], hv[7]);
  }
}

// ---------------------------------------------------------------------------
// K2a: partial row stats over one j-chunk (1024 keys = 16 tiles of 64).
// Grid (64 q-tiles, 4 chunks, 4 batches) = 1024 blocks; 4 waves x 16 q-rows.
// Writes per-row (m_c, Z_c) to pm/pz.
// ---------------------------------------------------------------------------
#define KH_OFF 0
#define KL_OFF 8192

__global__ __launch_bounds__(256) void stats_partial_kernel(
    const unsigned short* __restrict__ Qh, const unsigned short* __restrict__ Ql,
    const unsigned short* __restrict__ Kh, const unsigned short* __restrict__ Kl,
    float* __restrict__ pm, float* __restrict__ pz)
{
  __shared__ __align__(16) char sm[16384];

  const int t    = threadIdx.x;
  const int wv   = t >> 6;
  const int lane = t & 63;
  const int li   = lane & 15;
  const int lg   = lane >> 4;
  const int qt   = blockIdx.x;
  const int c    = blockIdx.y;
  const int b    = blockIdx.z;
  const int q0   = qt * 64 + wv * 16;
  const int sw   = li & 7;
  const int jt0  = c * 16;

  const int slotA0 = ((lg)     ^ sw) << 4;
  const int slotA1 = ((4 + lg) ^ sw) << 4;

  short8 qh0, qh1, ql0, ql1;
  {
    size_t base = ((size_t)(b * 4096 + q0 + li)) * 64 + lg * 8;
    qh0 = *(const short8*)(Qh + base);
    qh1 = *(const short8*)(Qh + base + 32);
    ql0 = *(const short8*)(Ql + base);
    ql1 = *(const short8*)(Ql + base + 32);
  }

  int sls[2] = { t, t + 256 };
  int st_off[2];
#pragma unroll
  for (int i = 0; i < 2; ++i) {
    int row = sls[i] >> 3, k16 = sls[i] & 7;
    st_off[i] = row * 128 + ((k16 ^ (row & 7)) << 4);
  }
  const size_t kbase = (size_t)b * 262144;

  float m = -3.0e38f, Z = 0.0f;
  uint4 rkh[2], rkl[2];
#pragma unroll
  for (int i = 0; i < 2; ++i) {
    rkh[i] = *(const uint4*)(Kh + kbase + (size_t)jt0 * 4096 + sls[i] * 8);
    rkl[i] = *(const uint4*)(Kl + kbase + (size_t)jt0 * 4096 + sls[i] * 8);
  }
#pragma unroll 1
  for (int jj = 0; jj < 16; ++jj) {
    __syncthreads();
#pragma unroll
    for (int i = 0; i < 2; ++i) {
      *(uint4*)(sm + KH_OFF + st_off[i]) = rkh[i];
      *(uint4*)(sm + KL_OFF + st_off[i]) = rkl[i];
    }
    __syncthreads();
    if (jj + 1 < 16) {
#pragma unroll
      for (int i = 0; i < 2; ++i) {
        rkh[i] = *(const uint4*)(Kh + kbase + (size_t)(jt0 + jj + 1) * 4096 + sls[i] * 8);
        rkl[i] = *(const uint4*)(Kl + kbase + (size_t)(jt0 + jj + 1) * 4096 + sls[i] * 8);
      }
    }
#pragma unroll
    for (int s = 0; s < 4; ++s) {
      f32x4 acc = {0.f, 0.f, 0.f, 0.f};
      fence_before_mfma(acc);
      const int rowb = (16 * s + li) * 128;
      short8 ah0 = *(const short8*)(sm + KH_OFF + rowb + slotA0);
      short8 al0 = *(const short8*)(sm + KL_OFF + rowb + slotA0);
      short8 ah1 = *(const short8*)(sm + KH_OFF + rowb + slotA1);
      short8 al1 = *(const short8*)(sm + KL_OFF + rowb + slotA1);
      mfma16(acc, ah0, qh0); mfma16(acc, ah0, ql0); mfma16(acc, al0, qh0);
      mfma16(acc, ah1, qh1); mfma16(acc, ah1, ql1); mfma16(acc, al1, qh1);
      fence_after_mfma(acc);
      float mx = fmaxf(fmaxf(acc[0], acc[1]), fmaxf(acc[2], acc[3]));
      float nm = fmaxf(m, mx);
      float sc = __builtin_exp2f(m - nm);
      Z = Z * sc + __builtin_exp2f(acc[0] - nm) + __builtin_exp2f(acc[1] - nm)
                 + __builtin_exp2f(acc[2] - nm) + __builtin_exp2f(acc[3] - nm);
      m = nm;
    }
  }
#pragma unroll
  for (int off = 16; off < 64; off <<= 1) {
    float om = __shfl_xor(m, off, 64);
    float oZ = __shfl_xor(Z, off, 64);
    float nm = fmaxf(m, om);
    Z = Z * __builtin_exp2f(m - nm) + oZ * __builtin_exp2f(om - nm);
    m = nm;
  }
  if (lane < 16) {
    int idx = ((b * 64 + qt) * 4 + c) * 64 + wv * 16 + li;
    pm[idx] = m;
    pz[idx] = Z;
  }
}

// ---------------------------------------------------------------------------
// K2b: combine 4 chunk partials -> L = M + log2(Z) per row. 64 blocks.
// ---------------------------------------------------------------------------
__global__ __launch_bounds__(256) void stats_combine_kernel(
    const float* __restrict__ pm, const float* __restrict__ pz,
    float* __restrict__ Lrow)
{
  int gr = blockIdx.x * 256 + threadIdx.x;     // [0, 16384)
  int b = gr >> 12, rem = gr & 4095;
  int qt = rem >> 6, row = rem & 63;
  int base = ((b * 64 + qt) * 4) * 64 + row;
  float m0 = pm[base], m1 = pm[base + 64], m2 = pm[base + 128], m3 = pm[base + 192];
  float M = fmaxf(fmaxf(m0, m1), fmaxf(m2, m3));
  float Z = pz[base]       * __builtin_exp2f(m0 - M)
          + pz[base + 64]  * __builtin_exp2f(m1 - M)
          + pz[base + 128] * __builtin_exp2f(m2 - M)
          + pz[base + 192] * __builtin_exp2f(m3 - M);
  Lrow[gr] = M + __builtin_log2f(Z);
}

// ---------------------------------------------------------------------------
// K2c: masked PV over one j-chunk; p' = 2^(s-L), mask p' > 2^-12;
// atomicAdd partial O into zeroed out. Grid (64,4,4) = 1024 blocks.
// ---------------------------------------------------------------------------
#define VT_OFF 16384
#define P_OFF  24576

__global__ __launch_bounds__(256) void pv_partial_kernel(
    const unsigned short* __restrict__ Qh, const unsigned short* __restrict__ Ql,
    const unsigned short* __restrict__ Kh, const unsigned short* __restrict__ Kl,
    const unsigned short* __restrict__ Vt, const float* __restrict__ Lrow,
    float* __restrict__ out)
{
  __shared__ __align__(16) char sm[32768];

  const int t    = threadIdx.x;
  const int wv   = t >> 6;
  const int lane = t & 63;
  const int li   = lane & 15;
  const int lg   = lane >> 4;
  const int qt   = blockIdx.x;
  const int c    = blockIdx.y;
  const int b    = blockIdx.z;
  const int q0   = qt * 64 + wv * 16;
  const int sw   = li & 7;
  const int jt0  = c * 16;

  const int slotA0 = ((lg)     ^ sw) << 4;
  const int slotA1 = ((4 + lg) ^ sw) << 4;

  short8 qh0, qh1, ql0, ql1;
  {
    size_t base = ((size_t)(b * 4096 + q0 + li)) * 64 + lg * 8;
    qh0 = *(const short8*)(Qh + base);
    qh1 = *(const short8*)(Qh + base + 32);
    ql0 = *(const short8*)(Ql + base);
    ql1 = *(const short8*)(Ql + base + 32);
  }
  const float L = Lrow[b * 4096 + q0 + li];

  int sls[2] = { t, t + 256 };
  int st_off[2];
#pragma unroll
  for (int i = 0; i < 2; ++i) {
    int row = sls[i] >> 3, k16 = sls[i] & 7;
    st_off[i] = row * 128 + ((k16 ^ (row & 7)) << 4);
  }
  const size_t kbase = (size_t)b * 262144;

  f32x4 o0 = {0.f,0.f,0.f,0.f}, o1 = {0.f,0.f,0.f,0.f};
  f32x4 o2 = {0.f,0.f,0.f,0.f}, o3 = {0.f,0.f,0.f,0.f};
  fence_before_mfma(o0); fence_before_mfma(o1);
  fence_before_mfma(o2); fence_before_mfma(o3);

  uint4 rkh[2], rkl[2], rvt[2];
#pragma unroll
  for (int i = 0; i < 2; ++i) {
    rkh[i] = *(const uint4*)(Kh + kbase + (size_t)jt0 * 4096 + sls[i] * 8);
    rkl[i] = *(const uint4*)(Kl + kbase + (size_t)jt0 * 4096 + sls[i] * 8);
    rvt[i] = *(const uint4*)(Vt + ((size_t)b * 64 + (sls[i] >> 3)) * 4096
                             + (size_t)jt0 * 64 + (sls[i] & 7) * 8);
  }
  const int pbase  = P_OFF + wv * 2048 + li * 128;
  const int pwslot = ((lg & 1) * 8);
#pragma unroll 1
  for (int jj = 0; jj < 16; ++jj) {
    __syncthreads();
#pragma unroll
    for (int i = 0; i < 2; ++i) {
      *(uint4*)(sm + KH_OFF + st_off[i]) = rkh[i];
      *(uint4*)(sm + KL_OFF + st_off[i]) = rkl[i];
      *(uint4*)(sm + VT_OFF + st_off[i]) = rvt[i];
    }
    __syncthreads();
    if (jj + 1 < 16) {
#pragma unroll
      for (int i = 0; i < 2; ++i) {
        rkh[i] = *(const uint4*)(Kh + kbase + (size_t)(jt0 + jj + 1) * 4096 + sls[i] * 8);
        rkl[i] = *(const uint4*)(Kl + kbase + (size_t)(jt0 + jj + 1) * 4096 + sls[i] * 8);
        rvt[i] = *(const uint4*)(Vt + ((size_t)b * 64 + (sls[i] >> 3)) * 4096
                                 + (size_t)(jt0 + jj + 1) * 64 + (sls[i] & 7) * 8);
      }
    }
#pragma unroll
    for (int s = 0; s < 4; ++s) {
      f32x4 acc = {0.f, 0.f, 0.f, 0.f};
      fence_before_mfma(acc);
      const int rowb = (16 * s + li) * 128;
      short8 ah0 = *(const short8*)(sm + KH_OFF + rowb + slotA0);
      short8 al0 = *(const short8*)(sm + KL_OFF + rowb + slotA0);
      short8 ah1 = *(const short8*)(sm + KH_OFF + rowb + slotA1);
      short8 al1 = *(const short8*)(sm + KL_OFF + rowb + slotA1);
      mfma16(acc, ah0, qh0); mfma16(acc, ah0, ql0); mfma16(acc, al0, qh0);
      mfma16(acc, ah1, qh1); mfma16(acc, ah1, ql1); mfma16(acc, al1, qh1);
      fence_after_mfma(acc);
      float p0 = __builtin_exp2f(acc[0] - L); p0 = (p0 > MASK_THR) ? p0 : 0.0f;
      float p1 = __builtin_exp2f(acc[1] - L); p1 = (p1 > MASK_THR) ? p1 : 0.0f;
      float p2 = __builtin_exp2f(acc[2] - L); p2 = (p2 > MASK_THR) ? p2 : 0.0f;
      float p3 = __builtin_exp2f(acc[3] - L); p3 = (p3 > MASK_THR) ? p3 : 0.0f;
      uint2 pw;
      pw.x = (unsigned int)f2bf(p0) | ((unsigned int)f2bf(p1) << 16);
      pw.y = (unsigned int)f2bf(p2) | ((unsigned int)f2bf(p3) << 16);
      *(uint2*)(sm + pbase + (((2 * s + (lg >> 1)) ^ sw) << 4) + pwslot) = pw;
    }
    short8 pa0 = *(const short8*)(sm + pbase + slotA0);
    short8 pa1 = *(const short8*)(sm + pbase + slotA1);
    {
      short8 vb0 = *(const short8*)(sm + VT_OFF + (li) * 128 + slotA0);
      short8 vb1 = *(const short8*)(sm + VT_OFF + (li) * 128 + slotA1);
      mfma16(o0, pa0, vb0); mfma16(o0, pa1, vb1);
      vb0 = *(const short8*)(sm + VT_OFF + (16 + li) * 128 + slotA0);
      vb1 = *(const short8*)(sm + VT_OFF + (16 + li) * 128 + slotA1);
      mfma16(o1, pa0, vb0); mfma16(o1, pa1, vb1);
      vb0 = *(const short8*)(sm + VT_OFF + (32 + li) * 128 + slotA0);
      vb1 = *(const short8*)(sm + VT_OFF + (32 + li) * 128 + slotA1);
      mfma16(o2, pa0, vb0); mfma16(o2, pa1, vb1);
      vb0 = *(const short8*)(sm + VT_OFF + (48 + li) * 128 + slotA0);
      vb1 = *(const short8*)(sm + VT_OFF + (48 + li) * 128 + slotA1);
      mfma16(o3, pa0, vb0); mfma16(o3, pa1, vb1);
    }
  }
  fence_after_mfma(o0); fence_after_mfma(o1);
  fence_after_mfma(o2); fence_after_mfma(o3);

  const size_t ob = ((size_t)b * 4096 + q0) * 64;
#pragma unroll
  for (int r = 0; r < 4; ++r) {
    size_t rowoff = ob + (size_t)(lg * 4 + r) * 64 + li;
    unsafeAtomicAdd(out + rowoff,      o0[r]);
    unsafeAtomicAdd(out + rowoff + 16, o1[r]);
    unsafeAtomicAdd(out + rowoff + 32, o2[r]);
    unsafeAtomicAdd(out + rowoff + 48, o3[r]);
  }
}

extern "C" void kernel_launch(void* const* d_in, const int* in_sizes, int n_in,
                              void* d_out, int out_size, void* d_ws, size_t ws_size,
                              hipStream_t stream) {
  (void)in_sizes; (void)n_in; (void)out_size; (void)ws_size;
  const float* x  = (const float*)d_in[0];
  const float* Wq = (const float*)d_in[1];
  const float* bq = (const float*)d_in[2];
  const float* Wk = (const float*)d_in[3];
  const float* bk = (const float*)d_in[4];
  const float* Wv = (const float*)d_in[5];
  const float* bv = (const float*)d_in[6];
  float* out = (float*)d_out;

  char* wsb = (char*)d_ws;
  const size_t A = 2097152;  // 2MB per bf16 array (1M elems)
  unsigned short* Qh = (unsigned short*)(wsb);
  unsigned short* Ql = (unsigned short*)(wsb + A);
  unsigned short* Kh = (unsigned short*)(wsb + 2 * A);
  unsigned short* Kl = (unsigned short*)(wsb + 3 * A);
  unsigned short* Vt = (unsigned short*)(wsb + 4 * A);
  float* pm   = (float*)(wsb + 5 * A);                 // 256KB
  float* pz   = (float*)(wsb + 5 * A + 262144);        // 256KB
  float* Lrow = (float*)(wsb + 5 * A + 524288);        // 64KB

  hipMemsetAsync(out, 0, (size_t)16384 * 64 * 4, stream);
  proj_qkv_kernel<<<dim3(512), dim3(256), 0, stream>>>(
      x, Wq, bq, Wk, bk, Wv, bv, Qh, Ql, Kh, Kl, Vt);
  stats_partial_kernel<<<dim3(64, 4, 4), dim3(256), 0, stream>>>(
      Qh, Ql, Kh, Kl, pm, pz);
  stats_combine_kernel<<<dim3(64), dim3(256), 0, stream>>>(pm, pz, Lrow);
  pv_partial_kernel<<<dim3(64, 4, 4), dim3(256), 0, stream>>>(
      Qh, Ql, Kh, Kl, Vt, Lrow, out);
}

// Round 5
// 296.042 us; speedup vs baseline: 1.4178x; 1.1758x over previous
//
#include <hip/hip_runtime.h>
#include <cstdint>
#include <cstddef>

typedef short short8 __attribute__((ext_vector_type(8)));
typedef float f32x4 __attribute__((ext_vector_type(4)));

#define LOG2E 1.44269504088896340736f
#define MASK_THR 2.44140625e-4f   // 2^-12 == 1/4096

__device__ inline unsigned short f2bf(float f) {
  unsigned int u = __float_as_uint(f);
  u += 0x7FFFu + ((u >> 16) & 1u);
  return (unsigned short)(u >> 16);
}
__device__ inline float bf2f(unsigned short s) {
  return __uint_as_float(((unsigned int)s) << 16);
}
__device__ inline void mfma16(f32x4 &acc, short8 a, short8 b) {
  asm volatile("v_mfma_f32_16x16x32_bf16 %0, %1, %2, %0"
               : "+v"(acc)
               : "v"(a), "v"(b));
}
__device__ inline void fence_after_mfma(f32x4 &x) {
  asm volatile("s_nop 7" : "+v"(x));
  asm volatile("s_nop 7" : "+v"(x));
}
__device__ inline void fence_before_mfma(f32x4 &x) {
  asm volatile("s_nop 1" : "+v"(x));
}
// VALU-write -> MFMA-read VGPR hazard fence: compiler inserts wait states for
// MFMA intrinsics but cannot see into our opaque asm. Tie s_nops to the
// VALU-produced operand before it feeds an MFMA.
__device__ inline void fence_frag(short8 &x) {
  asm volatile("s_nop 7" : "+v"(x));
  asm volatile("s_nop 7" : "+v"(x));
}

// ---------------------------------------------------------------------------
// prep_w: split W into bf16 hi/lo MFMA A-fragments.
// frag id = ((ch*12 + nt)*4 + lg)*16 + li holds W^T[n=nt*16+li][k=ch*32+lg*8..+7].
// Wq pre-scaled by log2e.
// ---------------------------------------------------------------------------
__global__ __launch_bounds__(256) void prep_w_kernel(
    const float* __restrict__ Wq, const float* __restrict__ Wk,
    const float* __restrict__ Wv,
    unsigned short* __restrict__ Wfh, unsigned short* __restrict__ Wfl)
{
  int id = blockIdx.x * 256 + threadIdx.x;   // 0..6143
  int li = id & 15, lg = (id >> 4) & 3, nt = (id >> 6) % 12, ch = id / 768;
  int n = nt * 16 + li;
  const float* W = (n < 64) ? Wq : ((n < 128) ? Wk : Wv);
  int col = n & 63;
  float sc = (n < 64) ? LOG2E : 1.0f;
  int k0 = ch * 32 + lg * 8;
  short8 hv, lv;
#pragma unroll
  for (int u = 0; u < 8; ++u) {
    float w = W[(k0 + u) * 64 + col] * sc;
    unsigned short h = f2bf(w);
    hv[u] = (short)h;
    lv[u] = (short)f2bf(w - bf2f(h));
  }
  *(short8*)(Wfh + (size_t)id * 8) = hv;
  *(short8*)(Wfl + (size_t)id * 8) = lv;
}

// ---------------------------------------------------------------------------
// proj: x[16384][256] f32 @ W fragments -> Qh/Ql, Kh/Kl (hi/lo bf16), Vt bf16
// transposed. 256 blocks x 4 waves; wave = 16 rows; compensated bf16 MFMA.
// xh/xl are VALU-produced MFMA operands -> explicit hazard fences.
// ---------------------------------------------------------------------------
__global__ __launch_bounds__(256) void proj_kernel(
    const float* __restrict__ x,
    const unsigned short* __restrict__ Wfh, const unsigned short* __restrict__ Wfl,
    const float* __restrict__ bq, const float* __restrict__ bk,
    const float* __restrict__ bv,
    unsigned short* __restrict__ Qh, unsigned short* __restrict__ Ql,
    unsigned short* __restrict__ Kh, unsigned short* __restrict__ Kl,
    unsigned short* __restrict__ Vt)
{
  __shared__ __align__(16) char sm[49408];
  const int t = threadIdx.x;
  const int wv = t >> 6, lane = t & 63, li = lane & 15, lg = lane >> 4;
  const int m0 = blockIdx.x * 64;

  f32x4 acc[12];
#pragma unroll
  for (int nt = 0; nt < 12; ++nt) { acc[nt] = (f32x4){0.f,0.f,0.f,0.f}; fence_before_mfma(acc[nt]); }

#pragma unroll 1
  for (int ch = 0; ch < 8; ++ch) {
    if (ch) __syncthreads();
#pragma unroll
    for (int i = 0; i < 3; ++i) {
      int sl = t + i * 256;
      *(uint4*)(sm + sl * 16)         = *(const uint4*)(Wfh + (size_t)ch * 6144 + sl * 8);
      *(uint4*)(sm + 12288 + sl * 16) = *(const uint4*)(Wfl + (size_t)ch * 6144 + sl * 8);
    }
    __syncthreads();
    const float* xp = x + (size_t)(m0 + wv * 16 + li) * 256 + ch * 32 + lg * 8;
    f32x4 xa = *(const f32x4*)xp;
    f32x4 xb = *(const f32x4*)(xp + 4);
    short8 xh, xl;
#pragma unroll
    for (int u = 0; u < 4; ++u) {
      unsigned short h = f2bf(xa[u]);
      xh[u] = (short)h; xl[u] = (short)f2bf(xa[u] - bf2f(h));
      unsigned short h2 = f2bf(xb[u]);
      xh[4 + u] = (short)h2; xl[4 + u] = (short)f2bf(xb[u] - bf2f(h2));
    }
    fence_frag(xh);
    fence_frag(xl);
#pragma unroll
    for (int nt = 0; nt < 12; ++nt) {
      short8 wh = *(const short8*)(sm + (nt * 64 + lg * 16 + li) * 16);
      short8 wl = *(const short8*)(sm + 12288 + (nt * 64 + lg * 16 + li) * 16);
      mfma16(acc[nt], wh, xh);
      mfma16(acc[nt], wh, xl);
      mfma16(acc[nt], wl, xh);
    }
  }
#pragma unroll
  for (int nt = 0; nt < 12; ++nt) fence_after_mfma(acc[nt]);
  __syncthreads();

  float* aL = (float*)(sm + wv * 12352);   // wave-private [16 rows][193 cols]
#pragma unroll
  for (int nt = 0; nt < 12; ++nt)
#pragma unroll
    for (int r = 0; r < 4; ++r)
      aL[li * 193 + nt * 16 + lg * 4 + r] = acc[nt][r];

  const int row = m0 + wv * 16 + li;
  const int b_idx = row >> 12, s0 = row & 4095;
  {
    unsigned int hq[8], lq[8];
#pragma unroll
    for (int c = 0; c < 16; c += 2) {
      float q0 = aL[li * 193 + lg * 16 + c]     + bq[lg * 16 + c] * LOG2E;
      float q1 = aL[li * 193 + lg * 16 + c + 1] + bq[lg * 16 + c + 1] * LOG2E;
      unsigned short h0 = f2bf(q0), h1 = f2bf(q1);
      hq[c >> 1] = (unsigned int)h0 | ((unsigned int)h1 << 16);
      lq[c >> 1] = (unsigned int)f2bf(q0 - bf2f(h0)) | ((unsigned int)f2bf(q1 - bf2f(h1)) << 16);
    }
    size_t o = (size_t)row * 64 + lg * 16;
    *(uint4*)(Qh + o)     = make_uint4(hq[0], hq[1], hq[2], hq[3]);
    *(uint4*)(Qh + o + 8) = make_uint4(hq[4], hq[5], hq[6], hq[7]);
    *(uint4*)(Ql + o)     = make_uint4(lq[0], lq[1], lq[2], lq[3]);
    *(uint4*)(Ql + o + 8) = make_uint4(lq[4], lq[5], lq[6], lq[7]);
  }
  {
    unsigned int hk[8], lk[8];
#pragma unroll
    for (int c = 0; c < 16; c += 2) {
      float k0 = aL[li * 193 + 64 + lg * 16 + c]     + bk[lg * 16 + c];
      float k1 = aL[li * 193 + 64 + lg * 16 + c + 1] + bk[lg * 16 + c + 1];
      unsigned short h0 = f2bf(k0), h1 = f2bf(k1);
      hk[c >> 1] = (unsigned int)h0 | ((unsigned int)h1 << 16);
      lk[c >> 1] = (unsigned int)f2bf(k0 - bf2f(h0)) | ((unsigned int)f2bf(k1 - bf2f(h1)) << 16);
    }
    size_t o = (size_t)row * 64 + lg * 16;
    *(uint4*)(Kh + o)     = make_uint4(hk[0], hk[1], hk[2], hk[3]);
    *(uint4*)(Kh + o + 8) = make_uint4(hk[4], hk[5], hk[6], hk[7]);
    *(uint4*)(Kl + o)     = make_uint4(lk[0], lk[1], lk[2], lk[3]);
    *(uint4*)(Kl + o + 8) = make_uint4(lk[4], lk[5], lk[6], lk[7]);
  }
#pragma unroll
  for (int c = 0; c < 16; ++c) {
    float vv = aL[li * 193 + 128 + lg * 16 + c] + bv[lg * 16 + c];
    Vt[((size_t)b_idx * 64 + lg * 16 + c) * 4096 + s0] = f2bf(vv);
  }
}

// ---------------------------------------------------------------------------
// stats_partial (r2-PROVEN kernel; only change: 8 chunks of 512 j instead of
// 4 of 1024, and the pm/pz index layout). Grid (64 qt, 8 chunks, 4 b).
// 4 waves x 16 q-rows; K staged in swizzled LDS; per-row (m, z) partials.
// ---------------------------------------------------------------------------
#define KH_OFF 0
#define KL_OFF 8192

__global__ __launch_bounds__(256) void stats_partial_kernel(
    const unsigned short* __restrict__ Qh, const unsigned short* __restrict__ Ql,
    const unsigned short* __restrict__ Kh, const unsigned short* __restrict__ Kl,
    float* __restrict__ pm, float* __restrict__ pz)
{
  __shared__ __align__(16) char sm[16384];

  const int t    = threadIdx.x;
  const int wv   = t >> 6;
  const int lane = t & 63;
  const int li   = lane & 15;
  const int lg   = lane >> 4;
  const int qt   = blockIdx.x;
  const int c    = blockIdx.y;
  const int b    = blockIdx.z;
  const int q0   = qt * 64 + wv * 16;
  const int sw   = li & 7;
  const int jt0  = c * 8;

  const int slotA0 = ((lg)     ^ sw) << 4;
  const int slotA1 = ((4 + lg) ^ sw) << 4;

  short8 qh0, qh1, ql0, ql1;
  {
    size_t base = ((size_t)(b * 4096 + q0 + li)) * 64 + lg * 8;
    qh0 = *(const short8*)(Qh + base);
    qh1 = *(const short8*)(Qh + base + 32);
    ql0 = *(const short8*)(Ql + base);
    ql1 = *(const short8*)(Ql + base + 32);
  }

  int sls[2] = { t, t + 256 };
  int st_off[2];
#pragma unroll
  for (int i = 0; i < 2; ++i) {
    int row = sls[i] >> 3, k16 = sls[i] & 7;
    st_off[i] = row * 128 + ((k16 ^ (row & 7)) << 4);
  }
  const size_t kbase = (size_t)b * 262144;

  float m = -3.0e38f, Z = 0.0f;
  uint4 rkh[2], rkl[2];
#pragma unroll
  for (int i = 0; i < 2; ++i) {
    rkh[i] = *(const uint4*)(Kh + kbase + (size_t)jt0 * 4096 + sls[i] * 8);
    rkl[i] = *(const uint4*)(Kl + kbase + (size_t)jt0 * 4096 + sls[i] * 8);
  }
#pragma unroll 1
  for (int jj = 0; jj < 8; ++jj) {
    __syncthreads();
#pragma unroll
    for (int i = 0; i < 2; ++i) {
      *(uint4*)(sm + KH_OFF + st_off[i]) = rkh[i];
      *(uint4*)(sm + KL_OFF + st_off[i]) = rkl[i];
    }
    __syncthreads();
    if (jj + 1 < 8) {
#pragma unroll
      for (int i = 0; i < 2; ++i) {
        rkh[i] = *(const uint4*)(Kh + kbase + (size_t)(jt0 + jj + 1) * 4096 + sls[i] * 8);
        rkl[i] = *(const uint4*)(Kl + kbase + (size_t)(jt0 + jj + 1) * 4096 + sls[i] * 8);
      }
    }
#pragma unroll
    for (int s = 0; s < 4; ++s) {
      f32x4 acc = {0.f, 0.f, 0.f, 0.f};
      fence_before_mfma(acc);
      const int rowb = (16 * s + li) * 128;
      short8 ah0 = *(const short8*)(sm + KH_OFF + rowb + slotA0);
      short8 al0 = *(const short8*)(sm + KL_OFF + rowb + slotA0);
      short8 ah1 = *(const short8*)(sm + KH_OFF + rowb + slotA1);
      short8 al1 = *(const short8*)(sm + KL_OFF + rowb + slotA1);
      mfma16(acc, ah0, qh0); mfma16(acc, ah0, ql0); mfma16(acc, al0, qh0);
      mfma16(acc, ah1, qh1); mfma16(acc, ah1, ql1); mfma16(acc, al1, qh1);
      fence_after_mfma(acc);
      float mx = fmaxf(fmaxf(acc[0], acc[1]), fmaxf(acc[2], acc[3]));
      float nm = fmaxf(m, mx);
      float sc = __builtin_exp2f(m - nm);
      Z = Z * sc + __builtin_exp2f(acc[0] - nm) + __builtin_exp2f(acc[1] - nm)
                 + __builtin_exp2f(acc[2] - nm) + __builtin_exp2f(acc[3] - nm);
      m = nm;
    }
  }
#pragma unroll
  for (int off = 16; off < 64; off <<= 1) {
    float om = __shfl_xor(m, off, 64);
    float oZ = __shfl_xor(Z, off, 64);
    float nm = fmaxf(m, om);
    Z = Z * __builtin_exp2f(m - nm) + oZ * __builtin_exp2f(om - nm);
    m = nm;
  }
  if (lane < 16) {
    int idx = (b * 4096 + q0 + lane) * 8 + c;
    pm[idx] = m;
    pz[idx] = Z;
  }
}

// ---------------------------------------------------------------------------
// combine: L[row] = M + log2(sum_c z_c * 2^(m_c - M)) over 8 chunks.
// ---------------------------------------------------------------------------
__global__ __launch_bounds__(256) void stats_combine_kernel(
    const float* __restrict__ pm, const float* __restrict__ pz,
    float* __restrict__ Lrow)
{
  int gr = blockIdx.x * 256 + threadIdx.x;     // [0, 16384)
  float M = -3.0e38f;
#pragma unroll
  for (int c = 0; c < 8; ++c) M = fmaxf(M, pm[gr * 8 + c]);
  float Z = 0.0f;
#pragma unroll
  for (int c = 0; c < 8; ++c)
    Z += pz[gr * 8 + c] * __builtin_exp2f(pm[gr * 8 + c] - M);
  Lrow[gr] = (Z > 0.0f) ? (M + __builtin_log2f(Z)) : M;
}

// ---------------------------------------------------------------------------
// pv_partial (r2-PROVEN kernel; only change: templated store path — partial
// buffers + reduce instead of atomics when ws permits). Grid (64 qt, 4 c, 4 b).
// p = 2^(s-L) in (0,1], mask p > 2^-12; output needs no normalization.
// ---------------------------------------------------------------------------
#define VT_OFF 16384
#define P_OFF  24576

template<int ATOMIC>
__global__ __launch_bounds__(256) void pv_partial_kernel(
    const unsigned short* __restrict__ Qh, const unsigned short* __restrict__ Ql,
    const unsigned short* __restrict__ Kh, const unsigned short* __restrict__ Kl,
    const unsigned short* __restrict__ Vt, const float* __restrict__ Lrow,
    float* __restrict__ outp)
{
  __shared__ __align__(16) char sm[32768];

  const int t    = threadIdx.x;
  const int wv   = t >> 6;
  const int lane = t & 63;
  const int li   = lane & 15;
  const int lg   = lane >> 4;
  const int qt   = blockIdx.x;
  const int c    = blockIdx.y;
  const int b    = blockIdx.z;
  const int q0   = qt * 64 + wv * 16;
  const int sw   = li & 7;
  const int jt0  = c * 16;

  const int slotA0 = ((lg)     ^ sw) << 4;
  const int slotA1 = ((4 + lg) ^ sw) << 4;

  short8 qh0, qh1, ql0, ql1;
  {
    size_t base = ((size_t)(b * 4096 + q0 + li)) * 64 + lg * 8;
    qh0 = *(const short8*)(Qh + base);
    qh1 = *(const short8*)(Qh + base + 32);
    ql0 = *(const short8*)(Ql + base);
    ql1 = *(const short8*)(Ql + base + 32);
  }
  const float L = Lrow[b * 4096 + q0 + li];

  int sls[2] = { t, t + 256 };
  int st_off[2];
#pragma unroll
  for (int i = 0; i < 2; ++i) {
    int row = sls[i] >> 3, k16 = sls[i] & 7;
    st_off[i] = row * 128 + ((k16 ^ (row & 7)) << 4);
  }
  const size_t kbase = (size_t)b * 262144;

  f32x4 o0 = {0.f,0.f,0.f,0.f}, o1 = {0.f,0.f,0.f,0.f};
  f32x4 o2 = {0.f,0.f,0.f,0.f}, o3 = {0.f,0.f,0.f,0.f};
  fence_before_mfma(o0); fence_before_mfma(o1);
  fence_before_mfma(o2); fence_before_mfma(o3);

  uint4 rkh[2], rkl[2], rvt[2];
#pragma unroll
  for (int i = 0; i < 2; ++i) {
    rkh[i] = *(const uint4*)(Kh + kbase + (size_t)jt0 * 4096 + sls[i] * 8);
    rkl[i] = *(const uint4*)(Kl + kbase + (size_t)jt0 * 4096 + sls[i] * 8);
    rvt[i] = *(const uint4*)(Vt + ((size_t)b * 64 + (sls[i] >> 3)) * 4096
                             + (size_t)jt0 * 64 + (sls[i] & 7) * 8);
  }
  const int pbase  = P_OFF + wv * 2048 + li * 128;
  const int pwslot = ((lg & 1) * 8);
#pragma unroll 1
  for (int jj = 0; jj < 16; ++jj) {
    __syncthreads();
#pragma unroll
    for (int i = 0; i < 2; ++i) {
      *(uint4*)(sm + KH_OFF + st_off[i]) = rkh[i];
      *(uint4*)(sm + KL_OFF + st_off[i]) = rkl[i];
      *(uint4*)(sm + VT_OFF + st_off[i]) = rvt[i];
    }
    __syncthreads();
    if (jj + 1 < 16) {
#pragma unroll
      for (int i = 0; i < 2; ++i) {
        rkh[i] = *(const uint4*)(Kh + kbase + (size_t)(jt0 + jj + 1) * 4096 + sls[i] * 8);
        rkl[i] = *(const uint4*)(Kl + kbase + (size_t)(jt0 + jj + 1) * 4096 + sls[i] * 8);
        rvt[i] = *(const uint4*)(Vt + ((size_t)b * 64 + (sls[i] >> 3)) * 4096
                                 + (size_t)(jt0 + jj + 1) * 64 + (sls[i] & 7) * 8);
      }
    }
#pragma unroll
    for (int s = 0; s < 4; ++s) {
      f32x4 acc = {0.f, 0.f, 0.f, 0.f};
      fence_before_mfma(acc);
      const int rowb = (16 * s + li) * 128;
      short8 ah0 = *(const short8*)(sm + KH_OFF + rowb + slotA0);
      short8 al0 = *(const short8*)(sm + KL_OFF + rowb + slotA0);
      short8 ah1 = *(const short8*)(sm + KH_OFF + rowb + slotA1);
      short8 al1 = *(const short8*)(sm + KL_OFF + rowb + slotA1);
      mfma16(acc, ah0, qh0); mfma16(acc, ah0, ql0); mfma16(acc, al0, qh0);
      mfma16(acc, ah1, qh1); mfma16(acc, ah1, ql1); mfma16(acc, al1, qh1);
      fence_after_mfma(acc);
      float p0 = __builtin_exp2f(acc[0] - L); p0 = (p0 > MASK_THR) ? p0 : 0.0f;
      float p1 = __builtin_exp2f(acc[1] - L); p1 = (p1 > MASK_THR) ? p1 : 0.0f;
      float p2 = __builtin_exp2f(acc[2] - L); p2 = (p2 > MASK_THR) ? p2 : 0.0f;
      float p3 = __builtin_exp2f(acc[3] - L); p3 = (p3 > MASK_THR) ? p3 : 0.0f;
      uint2 pw;
      pw.x = (unsigned int)f2bf(p0) | ((unsigned int)f2bf(p1) << 16);
      pw.y = (unsigned int)f2bf(p2) | ((unsigned int)f2bf(p3) << 16);
      *(uint2*)(sm + pbase + (((2 * s + (lg >> 1)) ^ sw) << 4) + pwslot) = pw;
    }
    short8 pa0 = *(const short8*)(sm + pbase + slotA0);
    short8 pa1 = *(const short8*)(sm + pbase + slotA1);
    {
      short8 vb0 = *(const short8*)(sm + VT_OFF + (li) * 128 + slotA0);
      short8 vb1 = *(const short8*)(sm + VT_OFF + (li) * 128 + slotA1);
      mfma16(o0, pa0, vb0); mfma16(o0, pa1, vb1);
      vb0 = *(const short8*)(sm + VT_OFF + (16 + li) * 128 + slotA0);
      vb1 = *(const short8*)(sm + VT_OFF + (16 + li) * 128 + slotA1);
      mfma16(o1, pa0, vb0); mfma16(o1, pa1, vb1);
      vb0 = *(const short8*)(sm + VT_OFF + (32 + li) * 128 + slotA0);
      vb1 = *(const short8*)(sm + VT_OFF + (32 + li) * 128 + slotA1);
      mfma16(o2, pa0, vb0); mfma16(o2, pa1, vb1);
      vb0 = *(const short8*)(sm + VT_OFF + (48 + li) * 128 + slotA0);
      vb1 = *(const short8*)(sm + VT_OFF + (48 + li) * 128 + slotA1);
      mfma16(o3, pa0, vb0); mfma16(o3, pa1, vb1);
    }
  }
  fence_after_mfma(o0); fence_after_mfma(o1);
  fence_after_mfma(o2); fence_after_mfma(o3);

  if (ATOMIC) {
    const size_t ob = ((size_t)b * 4096 + q0) * 64;
#pragma unroll
    for (int r = 0; r < 4; ++r) {
      size_t rowoff = ob + (size_t)(lg * 4 + r) * 64 + li;
      unsafeAtomicAdd(outp + rowoff,      o0[r]);
      unsafeAtomicAdd(outp + rowoff + 16, o1[r]);
      unsafeAtomicAdd(outp + rowoff + 32, o2[r]);
      unsafeAtomicAdd(outp + rowoff + 48, o3[r]);
    }
  } else {
    float* op = outp + (size_t)c * 1048576 + (size_t)b * 262144;
#pragma unroll
    for (int r = 0; r < 4; ++r) {
      size_t rowoff = (size_t)(q0 + lg * 4 + r) * 64 + li;
      op[rowoff]      = o0[r];
      op[rowoff + 16] = o1[r];
      op[rowoff + 32] = o2[r];
      op[rowoff + 48] = o3[r];
    }
  }
}

// ---------------------------------------------------------------------------
// reduce: out = sum_c Opart[c]   (no normalization needed)
// ---------------------------------------------------------------------------
__global__ __launch_bounds__(256) void reduce_kernel(
    const float* __restrict__ Opart, float* __restrict__ out)
{
  int idx = blockIdx.x * 256 + threadIdx.x;   // f32x4 units
  size_t e0 = (size_t)idx * 4;
  f32x4 s = *(const f32x4*)(Opart + e0);
  s += *(const f32x4*)(Opart + 1048576 + e0);
  s += *(const f32x4*)(Opart + 2097152 + e0);
  s += *(const f32x4*)(Opart + 3145728 + e0);
  *(f32x4*)(out + e0) = s;
}

extern "C" void kernel_launch(void* const* d_in, const int* in_sizes, int n_in,
                              void* d_out, int out_size, void* d_ws, size_t ws_size,
                              hipStream_t stream) {
  (void)in_sizes; (void)n_in; (void)out_size;
  const float* x  = (const float*)d_in[0];
  const float* Wq = (const float*)d_in[1];
  const float* bq = (const float*)d_in[2];
  const float* Wk = (const float*)d_in[3];
  const float* bk = (const float*)d_in[4];
  const float* Wv = (const float*)d_in[5];
  const float* bv = (const float*)d_in[6];
  float* out = (float*)d_out;

  char* wsb = (char*)d_ws;
  unsigned short* Qh  = (unsigned short*)(wsb);
  unsigned short* Ql  = (unsigned short*)(wsb + 2097152);
  unsigned short* Kh  = (unsigned short*)(wsb + 4194304);
  unsigned short* Kl  = (unsigned short*)(wsb + 6291456);
  unsigned short* Vt  = (unsigned short*)(wsb + 8388608);
  unsigned short* Wfh = (unsigned short*)(wsb + 10485760);
  unsigned short* Wfl = (unsigned short*)(wsb + 10584064);
  float*         Lrow = (float*)(wsb + 10682368);  // 64KB
  float*           pm = (float*)(wsb + 10747904);  // 512KB
  float*           pz = (float*)(wsb + 11272192);  // 512KB
  float*        Opart = (float*)(wsb + 11796480);  // 16MB (path A)
  const bool pathA = ws_size >= (size_t)11796480 + 16777216;

  prep_w_kernel<<<dim3(24), dim3(256), 0, stream>>>(Wq, Wk, Wv, Wfh, Wfl);
  proj_kernel<<<dim3(256), dim3(256), 0, stream>>>(
      x, Wfh, Wfl, bq, bk, bv, Qh, Ql, Kh, Kl, Vt);
  stats_partial_kernel<<<dim3(64, 8, 4), dim3(256), 0, stream>>>(
      Qh, Ql, Kh, Kl, pm, pz);
  stats_combine_kernel<<<dim3(64), dim3(256), 0, stream>>>(pm, pz, Lrow);
  if (pathA) {
    pv_partial_kernel<0><<<dim3(64, 4, 4), dim3(256), 0, stream>>>(
        Qh, Ql, Kh, Kl, Vt, Lrow, Opart);
    reduce_kernel<<<dim3(1024), dim3(256), 0, stream>>>(Opart, out);
  } else {
    hipMemsetAsync(out, 0, (size_t)4194304, stream);
    pv_partial_kernel<1><<<dim3(64, 4, 4), dim3(256), 0, stream>>>(
        Qh, Ql, Kh, Kl, Vt, Lrow, out);
  }
}